// Round 4
// baseline (155.936 us; speedup 1.0000x reference)
//
#include <hip/hip_runtime.h>
#include <hip/hip_bf16.h>

// Problem constants (match the JAX reference).
#define BB     16
#define QQ     2048
#define NCLS   2
#define DBOX   6
#define TT     1024
#define ROWS   (BB * QQ)          // 32768 (b,q) rows
#define TPB    256                // threads per block
#define TPT    4                  // targets per thread: 256*4 = 1024 = TT
#define RPB    32                 // rows per block: grid = 32768/32 = 1024 blocks
#define RCHUNK 4                  // rows processed together (ILP / MLP)

typedef float v4f __attribute__((ext_vector_type(4)));  // native vector: ok for nontemporal builtin

__global__ __launch_bounds__(TPB) void hungarian_cost_kernel(
    const float* __restrict__ logits,   // (ROWS, NCLS) f32
    const float* __restrict__ boxes,    // (ROWS, DBOX) f32
    const int*   __restrict__ labels,   // (TT,) int32
    const float* __restrict__ tboxes,   // (TT, DBOX) f32
    float*       __restrict__ out)      // (ROWS, TT) f32
{
    const int tid = threadIdx.x;
    const int t0  = tid * TPT;

    // --- Preload this thread's 4 targets into registers (once per block) ---
    float tb[TPT][DBOX];
    float w[TPT];
#pragma unroll
    for (int j = 0; j < TPT; ++j) {
        const int t = t0 + j;
#pragma unroll
        for (int d = 0; d < DBOX; ++d) tb[j][d] = tboxes[t * DBOX + d];
        w[j] = (float)labels[t];    // label in {0,1} -> selector weight
    }

    const int row0 = blockIdx.x * RPB;

#pragma unroll 1
    for (int rc = 0; rc < RPB; rc += RCHUNK) {
        // ---- Stage 4 rows' uniform inputs (loads issue together) ----
        float l0v[RCHUNK], l1v[RCHUNK], qb[RCHUNK][DBOX];
#pragma unroll
        for (int r = 0; r < RCHUNK; ++r) {
            const int row = row0 + rc + r;     // wave-uniform
            l0v[r] = logits[row * NCLS + 0];
            l1v[r] = logits[row * NCLS + 1];
#pragma unroll
            for (int d = 0; d < DBOX; ++d) qb[r][d] = boxes[row * DBOX + d];
        }

        // ---- 4 independent softmax chains ----
        float p0v[RCHUNK], d10v[RCHUNK];
#pragma unroll
        for (int r = 0; r < RCHUNK; ++r) {
            const float e0  = __expf(l0v[r]);
            const float e1  = __expf(l1v[r]);
            const float inv = 1.0f / (e0 + e1);
            p0v[r]  = e0 * inv;
            d10v[r] = (e1 - e0) * inv;         // p1 - p0
        }

        // ---- Compute + store 4 rows (4 stores in flight) ----
#pragma unroll
        for (int r = 0; r < RCHUNK; ++r) {
            const int row = row0 + rc + r;
            float c[TPT];
#pragma unroll
            for (int j = 0; j < TPT; ++j) {
                float s = 0.0f;
#pragma unroll
                for (int d = 0; d < DBOX; ++d) s += fabsf(qb[r][d] - tb[j][d]);
                c[j] = 5.0f * s - (p0v[r] + w[j] * d10v[r]);
            }
            v4f v = { c[0], c[1], c[2], c[3] };
            __builtin_nontemporal_store(v,
                reinterpret_cast<v4f*>(out + (size_t)row * TT + t0));
        }
    }
}

extern "C" void kernel_launch(void* const* d_in, const int* in_sizes, int n_in,
                              void* d_out, int out_size, void* d_ws, size_t ws_size,
                              hipStream_t stream) {
    const float* logits = (const float*)d_in[0];   // (B,Q,NCLS) f32
    const float* boxes  = (const float*)d_in[1];   // (B,Q,DBOX) f32
    const int*   labels = (const int*)  d_in[2];   // (T,) int
    const float* tboxes = (const float*)d_in[3];   // (T,DBOX) f32
    float*       out    = (float*)d_out;           // (B,Q,T) f32

    const int grid = ROWS / RPB;  // 1024
    hungarian_cost_kernel<<<grid, TPB, 0, stream>>>(logits, boxes, labels, tboxes, out);
}